// Round 4
// baseline (137.349 us; speedup 1.0000x reference)
//
#include <hip/hip_runtime.h>
#include <stdint.h>

#define N_NODES 10000
#define M_PAD   10112    // 79 * 128
#define N_EDGES 160000
#define DIM     512
#define N_ELEMS 5120000  // N_NODES*DIM
#define NEG_SLOPE 0.25f

typedef short          short8   __attribute__((ext_vector_type(8)));
typedef unsigned short ushort8v __attribute__((ext_vector_type(8)));
typedef __bf16         bf16x8   __attribute__((ext_vector_type(8)));
typedef float          f32x4    __attribute__((ext_vector_type(4)));

__device__ __forceinline__ unsigned short f2bf(float f) {   // RNE f32->bf16
    uint32_t u = __builtin_bit_cast(uint32_t, f);
    uint32_t r = (u + 0x7fffu + ((u >> 16) & 1u)) >> 16;
    return (unsigned short)r;
}
__device__ __forceinline__ float b2f(unsigned short u) {
    return __builtin_bit_cast(float, (uint32_t)u << 16);
}

// ---------------- threefry2x32-20, key = jax.random.key(42) = (0, 42) ----------------
__device__ __forceinline__ uint32_t rotl32(uint32_t x, uint32_t d) {
    return (x << d) | (x >> (32u - d));
}
__device__ __forceinline__ void threefry_42(uint32_t x0, uint32_t x1,
                                            uint32_t& o0, uint32_t& o1) {
    const uint32_t ks0 = 0u, ks1 = 42u, ks2 = 0x1BD11BDAu ^ 42u;
    x0 += ks0; x1 += ks1;
#define TF_R4(a,b,c,d) \
    x0 += x1; x1 = rotl32(x1,a); x1 ^= x0; \
    x0 += x1; x1 = rotl32(x1,b); x1 ^= x0; \
    x0 += x1; x1 = rotl32(x1,c); x1 ^= x0; \
    x0 += x1; x1 = rotl32(x1,d); x1 ^= x0;
    TF_R4(13,15,26,6);  x0 += ks1; x1 += ks2 + 1u;
    TF_R4(17,29,16,24); x0 += ks2; x1 += ks0 + 2u;
    TF_R4(13,15,26,6);  x0 += ks0; x1 += ks1 + 3u;
    TF_R4(17,29,16,24); x0 += ks1; x1 += ks2 + 4u;
    TF_R4(13,15,26,6);  x0 += ks2; x1 += ks0 + 5u;
#undef TF_R4
    o0 = x0; o1 = x1;
}

// ---------------- fused prep: convert H, transpose W1/W2, dropout mask, zero cnt --------
#define CONV_BLKS 5000   // 5.12M floats / 4 per thread / 256 threads
#define TR_BLKS   64     // 8x8 tiles of 64x64
#define MASK_BLKS 625    // 160000 uint32 words / 256
#define ZERO_BLKS 10

__device__ __forceinline__ void transpose_tile(const float* __restrict__ W,
                                               unsigned short* __restrict__ WT,
                                               int tile, float (*ts)[65]) {
    int k0 = (tile & 7) * 64, n0 = (tile >> 3) * 64;
    int tx = threadIdx.x & 15, ty = threadIdx.x >> 4;
    #pragma unroll
    for (int i = 0; i < 4; ++i) {
        int k = i * 16 + ty;
        float4 v = *(const float4*)&W[(size_t)(k0 + k) * DIM + n0 + tx * 4];
        ts[k][tx * 4 + 0] = v.x; ts[k][tx * 4 + 1] = v.y;
        ts[k][tx * 4 + 2] = v.z; ts[k][tx * 4 + 3] = v.w;
    }
    __syncthreads();
    #pragma unroll
    for (int i = 0; i < 4; ++i) {
        int n = i * 16 + ty;
        ushort4 o;
        o.x = f2bf(ts[tx * 4 + 0][n]); o.y = f2bf(ts[tx * 4 + 1][n]);
        o.z = f2bf(ts[tx * 4 + 2][n]); o.w = f2bf(ts[tx * 4 + 3][n]);
        *(ushort4*)&WT[(size_t)(n0 + n) * DIM + k0 + tx * 4] = o;
    }
}

__global__ __launch_bounds__(256)
void prep_kernel(const float* __restrict__ H, const float* __restrict__ W1,
                 const float* __restrict__ W2, unsigned short* __restrict__ Abf,
                 unsigned short* __restrict__ WT1, unsigned short* __restrict__ WT2,
                 uint32_t* __restrict__ mask, int* __restrict__ cnt) {
    __shared__ float ts[64][65];
    int b = blockIdx.x;
    if (b < CONV_BLKS) {
        int i = b * 256 + threadIdx.x;           // one float4 per thread
        float4 v = ((const float4*)H)[i];
        ushort4 o;
        o.x = f2bf(v.x); o.y = f2bf(v.y); o.z = f2bf(v.z); o.w = f2bf(v.w);
        ((ushort4*)Abf)[i] = o;
    } else if (b < CONV_BLKS + TR_BLKS) {
        transpose_tile(W1, WT1, b - CONV_BLKS, ts);
    } else if (b < CONV_BLKS + 2 * TR_BLKS) {
        transpose_tile(W2, WT2, b - CONV_BLKS - TR_BLKS, ts);
    } else if (b < CONV_BLKS + 2 * TR_BLKS + MASK_BLKS) {
        int w = (b - CONV_BLKS - 2 * TR_BLKS) * 256 + threadIdx.x;  // one uint32 word
        uint32_t base = (uint32_t)w * 32;
        uint32_t m = 0;
        #pragma unroll
        for (int j = 0; j < 32; ++j) {
            uint32_t o0, o1;
            threefry_42(0u, base + j, o0, o1);
            uint32_t bits = o0 ^ o1;             // keep iff MSB clear (u < 0.5)
            m |= (uint32_t)(((int)bits >= 0) ? 1u : 0u) << j;
        }
        mask[w] = m;
    } else {
        int i = (b - CONV_BLKS - 2 * TR_BLKS - MASK_BLKS) * 1024 + threadIdx.x * 4;
        #pragma unroll
        for (int j = 0; j < 4; ++j)
            if (i + j < N_NODES) cnt[i + j] = 0;
    }
}

// ---------------- CSR build ----------------
__global__ void hist_kernel(const int* __restrict__ rows, int* __restrict__ cnt) {
    int e = blockIdx.x * blockDim.x + threadIdx.x;
    if (e < N_EDGES) atomicAdd(&cnt[rows[e]], 1);
}

__global__ __launch_bounds__(1024)
void scan_kernel(const int* __restrict__ cnt, int* __restrict__ rs, int* __restrict__ cur) {
    __shared__ int s[1024];
    int t = threadIdx.x;
    int base_i = t * 10;
    int local[10];
    int p = 0;
    if (t < 1000) {
        #pragma unroll
        for (int j = 0; j < 10; ++j) { local[j] = cnt[base_i + j]; p += local[j]; }
    }
    s[t] = p;
    __syncthreads();
    for (int off = 1; off < 1024; off <<= 1) {
        int v = (t >= off) ? s[t - off] : 0;
        __syncthreads();
        s[t] += v;
        __syncthreads();
    }
    if (t < 1000) {
        int run = s[t] - p;
        #pragma unroll
        for (int j = 0; j < 10; ++j) {
            rs[base_i + j]  = run;
            cur[base_i + j] = run;
            run += local[j];
        }
        if (t == 999) rs[N_NODES] = run;
    }
}

__global__ void scatter_kernel(const int* __restrict__ rows, const int* __restrict__ cols,
                               const float* __restrict__ vals, int* __restrict__ cur,
                               int* __restrict__ scol, float* __restrict__ sval) {
    int e = blockIdx.x * blockDim.x + threadIdx.x;
    if (e < N_EDGES) {
        int r = rows[e];
        int p = atomicAdd(&cur[r], 1);
        scol[p] = cols[e];
        sval[p] = vals[e];
    }
}

// ---------------- bf16 MFMA GEMM: C[M][512] = A[M][512] @ WT[n][k]^T ----------------
// 128x64 tile, BK=64, 256 threads = 4 waves (2x2), each wave 64x32 (4x2 frags).
// LDS [row][8 slots of 16B], slot XOR-swizzled by (row&7); linear LDS dest for
// global_load_lds + inverse-swizzled GLOBAL source (rule #21, involution).
__global__ __launch_bounds__(256)
void mfma_gemm(const unsigned short* __restrict__ A, const unsigned short* __restrict__ BT,
               unsigned short* __restrict__ C, int M) {
    __shared__ short8 As[128 * 8];   // 16KB
    __shared__ short8 Bs[64 * 8];    //  8KB
    int tid  = threadIdx.x;
    int wid  = tid >> 6, lane = tid & 63;
    int bm   = blockIdx.x * 128;
    int bn   = blockIdx.y * 64;
    int wm   = (wid >> 1) * 64, wn = (wid & 1) * 32;

    f32x4 acc[4][2] = {};
    int srow = lane >> 3, sslot = lane & 7;

    for (int k0 = 0; k0 < DIM; k0 += 64) {
        #pragma unroll
        for (int c = 0; c < 4; ++c) {            // A: 128 rows = 4 issues x (4 waves x 8 rows)
            int r0 = c * 32 + wid * 8;
            int r  = r0 + srow;
            int ks = sslot ^ (r & 7);
            const unsigned short* ga = A + (size_t)(bm + r) * DIM + k0 + ks * 8;
            __builtin_amdgcn_global_load_lds(
                (const __attribute__((address_space(1))) void*)ga,
                (__attribute__((address_space(3))) void*)&As[r0 * 8], 16, 0, 0);
        }
        #pragma unroll
        for (int c = 0; c < 2; ++c) {            // B: 64 rows = 2 issues
            int r0 = c * 32 + wid * 8;
            int r  = r0 + srow;
            int ks = sslot ^ (r & 7);
            const unsigned short* gb = BT + (size_t)(bn + r) * DIM + k0 + ks * 8;
            __builtin_amdgcn_global_load_lds(
                (const __attribute__((address_space(1))) void*)gb,
                (__attribute__((address_space(3))) void*)&Bs[r0 * 8], 16, 0, 0);
        }
        __syncthreads();

        int lrow = lane & 15;
        int kgrp = lane >> 4;
        #pragma unroll
        for (int ks = 0; ks < 2; ++ks) {
            short8 af[4], bfr[2];
            #pragma unroll
            for (int i = 0; i < 4; ++i) {
                int r = wm + i * 16 + lrow;
                af[i] = As[r * 8 + ((ks * 4 + kgrp) ^ (r & 7))];
            }
            #pragma unroll
            for (int j = 0; j < 2; ++j) {
                int n = wn + j * 16 + lrow;
                bfr[j] = Bs[n * 8 + ((ks * 4 + kgrp) ^ (n & 7))];
            }
            #pragma unroll
            for (int i = 0; i < 4; ++i)
                #pragma unroll
                for (int j = 0; j < 2; ++j)
                    acc[i][j] = __builtin_amdgcn_mfma_f32_16x16x32_bf16(
                        __builtin_bit_cast(bf16x8, af[i]),
                        __builtin_bit_cast(bf16x8, bfr[j]), acc[i][j], 0, 0, 0);
        }
        __syncthreads();
    }

    // C/D layout: col=lane&15, row=(lane>>4)*4+reg  [m89]
    int crow = (lane >> 4) * 4;
    int ccol = lane & 15;
    #pragma unroll
    for (int i = 0; i < 4; ++i) {
        #pragma unroll
        for (int r = 0; r < 4; ++r) {
            int row = bm + wm + i * 16 + crow + r;
            if (row < M) {
                size_t base = (size_t)row * DIM + bn + wn + ccol;
                #pragma unroll
                for (int j = 0; j < 2; ++j)
                    C[base + j * 16] = f2bf(acc[i][j][r]);
            }
        }
    }
}

// ---------------- SpMM: 1 wave per row, lane owns 8 cols (16B loads), 4-edge unroll ----
__global__ __launch_bounds__(256)
void spmm1_kernel(const unsigned short* __restrict__ X, const int* __restrict__ rs,
                  const int* __restrict__ scol, const float* __restrict__ sval,
                  const float* __restrict__ bias, const uint8_t* __restrict__ mask,
                  unsigned short* __restrict__ hout) {
    int row  = blockIdx.x * 4 + (threadIdx.x >> 6);
    int lane = threadIdx.x & 63;
    int start = rs[row], end = rs[row + 1];
    const ushort8v* X8 = (const ushort8v*)X;     // row stride = 64 ushort8
    float a[8] = {}, b[8] = {};
    int p = start;
    for (; p + 3 < end; p += 4) {
        int   c0 = scol[p],     c1 = scol[p + 1], c2 = scol[p + 2], c3 = scol[p + 3];
        float v0 = sval[p],     v1 = sval[p + 1], v2 = sval[p + 2], v3 = sval[p + 3];
        ushort8v x0 = X8[(size_t)c0 * 64 + lane];
        ushort8v x1 = X8[(size_t)c1 * 64 + lane];
        ushort8v x2 = X8[(size_t)c2 * 64 + lane];
        ushort8v x3 = X8[(size_t)c3 * 64 + lane];
        #pragma unroll
        for (int e = 0; e < 8; ++e) {
            a[e] = fmaf(v0, b2f(x0[e]), a[e]);
            b[e] = fmaf(v1, b2f(x1[e]), b[e]);
            a[e] = fmaf(v2, b2f(x2[e]), a[e]);
            b[e] = fmaf(v3, b2f(x3[e]), b[e]);
        }
    }
    for (; p < end; ++p) {
        int c0 = scol[p]; float v0 = sval[p];
        ushort8v x0 = X8[(size_t)c0 * 64 + lane];
        #pragma unroll
        for (int e = 0; e < 8; ++e) a[e] = fmaf(v0, b2f(x0[e]), a[e]);
    }
    float4 bi0 = ((const float4*)bias)[lane * 2];
    float4 bi1 = ((const float4*)bias)[lane * 2 + 1];
    float bb[8] = { bi0.x, bi0.y, bi0.z, bi0.w, bi1.x, bi1.y, bi1.z, bi1.w };
    uint32_t mb = mask[(size_t)row * 64 + lane];
    ushort8v o;
    #pragma unroll
    for (int e = 0; e < 8; ++e) {
        float v = a[e] + b[e] + bb[e];
        v = (v >= 0.f) ? v : NEG_SLOPE * v;
        v = ((mb >> e) & 1u) ? v * 2.0f : 0.0f;
        o[e] = f2bf(v);
    }
    ((ushort8v*)hout)[(size_t)row * 64 + lane] = o;
}

__global__ __launch_bounds__(256)
void spmm2_kernel(const unsigned short* __restrict__ X, const int* __restrict__ rs,
                  const int* __restrict__ scol, const float* __restrict__ sval,
                  const float* __restrict__ bias, float* __restrict__ out) {
    int row  = blockIdx.x * 4 + (threadIdx.x >> 6);
    int lane = threadIdx.x & 63;
    int start = rs[row], end = rs[row + 1];
    const ushort8v* X8 = (const ushort8v*)X;
    float a[8] = {}, b[8] = {};
    int p = start;
    for (; p + 3 < end; p += 4) {
        int   c0 = scol[p],     c1 = scol[p + 1], c2 = scol[p + 2], c3 = scol[p + 3];
        float v0 = sval[p],     v1 = sval[p + 1], v2 = sval[p + 2], v3 = sval[p + 3];
        ushort8v x0 = X8[(size_t)c0 * 64 + lane];
        ushort8v x1 = X8[(size_t)c1 * 64 + lane];
        ushort8v x2 = X8[(size_t)c2 * 64 + lane];
        ushort8v x3 = X8[(size_t)c3 * 64 + lane];
        #pragma unroll
        for (int e = 0; e < 8; ++e) {
            a[e] = fmaf(v0, b2f(x0[e]), a[e]);
            b[e] = fmaf(v1, b2f(x1[e]), b[e]);
            a[e] = fmaf(v2, b2f(x2[e]), a[e]);
            b[e] = fmaf(v3, b2f(x3[e]), b[e]);
        }
    }
    for (; p < end; ++p) {
        int c0 = scol[p]; float v0 = sval[p];
        ushort8v x0 = X8[(size_t)c0 * 64 + lane];
        #pragma unroll
        for (int e = 0; e < 8; ++e) a[e] = fmaf(v0, b2f(x0[e]), a[e]);
    }
    float4 bi0 = ((const float4*)bias)[lane * 2];
    float4 bi1 = ((const float4*)bias)[lane * 2 + 1];
    float r[8] = { bi0.x, bi0.y, bi0.z, bi0.w, bi1.x, bi1.y, bi1.z, bi1.w };
    #pragma unroll
    for (int e = 0; e < 8; ++e) {
        float v = a[e] + b[e] + r[e];
        r[e] = (v >= 0.f) ? v : NEG_SLOPE * v;
    }
    float4 o0 = make_float4(r[0], r[1], r[2], r[3]);
    float4 o1 = make_float4(r[4], r[5], r[6], r[7]);
    ((float4*)out)[(size_t)row * 128 + lane * 2]     = o0;
    ((float4*)out)[(size_t)row * 128 + lane * 2 + 1] = o1;
}

// ---------------- launch ----------------
extern "C" void kernel_launch(void* const* d_in, const int* in_sizes, int n_in,
                              void* d_out, int out_size, void* d_ws, size_t ws_size,
                              hipStream_t stream) {
    const float* H    = (const float*)d_in[0];
    const int*   rows = (const int*)  d_in[1];
    const int*   cols = (const int*)  d_in[2];
    const float* vals = (const float*)d_in[3];
    const float* W1   = (const float*)d_in[4];
    const float* b1   = (const float*)d_in[5];
    const float* W2   = (const float*)d_in[6];
    const float* b2   = (const float*)d_in[7];
    float* out = (float*)d_out;

    char* ws = (char*)d_ws;
    size_t off = 0;
    auto alloc = [&](size_t bytes) -> void* {
        off = (off + 255) & ~(size_t)255;
        void* p = ws + off;
        off += bytes;
        return p;
    };
    int*      cnt  = (int*)     alloc((size_t)N_NODES * 4);
    int*      rs   = (int*)     alloc((size_t)(N_NODES + 1) * 4);
    int*      cur  = (int*)     alloc((size_t)N_NODES * 4);
    int*      scol = (int*)     alloc((size_t)N_EDGES * 4);
    float*    sval = (float*)   alloc((size_t)N_EDGES * 4);
    uint32_t* mask = (uint32_t*)alloc((size_t)N_ELEMS / 8);          // 640KB bit-mask
    unsigned short* WT1 = (unsigned short*)alloc((size_t)DIM * DIM * 2);
    unsigned short* WT2 = (unsigned short*)alloc((size_t)DIM * DIM * 2);
    unsigned short* Abf = (unsigned short*)alloc((size_t)M_PAD * DIM * 2);
    unsigned short* hbf = (unsigned short*)alloc((size_t)M_PAD * DIM * 2);
    unsigned short* Xbf = (unsigned short*)alloc((size_t)N_NODES * DIM * 2);

    int prep_blocks = CONV_BLKS + 2 * TR_BLKS + MASK_BLKS + ZERO_BLKS;
    prep_kernel<<<prep_blocks, 256, 0, stream>>>(H, W1, W2, Abf, WT1, WT2, mask, cnt);
    hist_kernel<<<(N_EDGES + 255) / 256, 256, 0, stream>>>(rows, cnt);
    scan_kernel<<<1, 1024, 0, stream>>>(cnt, rs, cur);
    scatter_kernel<<<(N_EDGES + 255) / 256, 256, 0, stream>>>(rows, cols, vals, cur, scol, sval);

    dim3 ggrid(M_PAD / 128, DIM / 64);
    mfma_gemm<<<ggrid, 256, 0, stream>>>(Abf, WT1, Xbf, N_NODES);
    spmm1_kernel<<<N_NODES / 4, 256, 0, stream>>>(Xbf, rs, scol, sval, b1,
                                                  (const uint8_t*)mask, hbf);
    mfma_gemm<<<ggrid, 256, 0, stream>>>(hbf, WT2, Xbf, N_NODES);
    spmm2_kernel<<<N_NODES / 4, 256, 0, stream>>>(Xbf, rs, scol, sval, b2, out);
}

// Round 5
// 135.512 us; speedup vs baseline: 1.0136x; 1.0136x over previous
//
#include <hip/hip_runtime.h>
#include <stdint.h>

#define N_NODES 10000
#define M_PAD   10112    // 79 * 128
#define N_EDGES 160000
#define DIM     512
#define N_ELEMS 5120000  // N_NODES*DIM
#define NEG_SLOPE 0.25f

typedef short          short8   __attribute__((ext_vector_type(8)));
typedef __bf16         bf16x8   __attribute__((ext_vector_type(8)));
typedef float          f32x4    __attribute__((ext_vector_type(4)));

__device__ __forceinline__ unsigned short f2bf(float f) {   // RNE f32->bf16
    uint32_t u = __builtin_bit_cast(uint32_t, f);
    uint32_t r = (u + 0x7fffu + ((u >> 16) & 1u)) >> 16;
    return (unsigned short)r;
}
__device__ __forceinline__ float b2f(unsigned short u) {
    return __builtin_bit_cast(float, (uint32_t)u << 16);
}

// ---------------- threefry2x32-20, key = jax.random.key(42) = (0, 42) ----------------
__device__ __forceinline__ uint32_t rotl32(uint32_t x, uint32_t d) {
    return (x << d) | (x >> (32u - d));
}
__device__ __forceinline__ void threefry_42(uint32_t x0, uint32_t x1,
                                            uint32_t& o0, uint32_t& o1) {
    const uint32_t ks0 = 0u, ks1 = 42u, ks2 = 0x1BD11BDAu ^ 42u;
    x0 += ks0; x1 += ks1;
#define TF_R4(a,b,c,d) \
    x0 += x1; x1 = rotl32(x1,a); x1 ^= x0; \
    x0 += x1; x1 = rotl32(x1,b); x1 ^= x0; \
    x0 += x1; x1 = rotl32(x1,c); x1 ^= x0; \
    x0 += x1; x1 = rotl32(x1,d); x1 ^= x0;
    TF_R4(13,15,26,6);  x0 += ks1; x1 += ks2 + 1u;
    TF_R4(17,29,16,24); x0 += ks2; x1 += ks0 + 2u;
    TF_R4(13,15,26,6);  x0 += ks0; x1 += ks1 + 3u;
    TF_R4(17,29,16,24); x0 += ks1; x1 += ks2 + 4u;
    TF_R4(13,15,26,6);  x0 += ks2; x1 += ks0 + 5u;
#undef TF_R4
    o0 = x0; o1 = x1;
}

// ---------------- fused prep: convert H, transpose W1/W2, dropout mask, zero cnt --------
#define CONV_BLKS 5000   // 5.12M floats / 4 per thread / 256 threads
#define TR_BLKS   64     // 8x8 tiles of 64x64
#define MASK_BLKS 625    // 160000 uint32 words / 256
#define ZERO_BLKS 10

__device__ __forceinline__ void transpose_tile(const float* __restrict__ W,
                                               unsigned short* __restrict__ WT,
                                               int tile, float (*ts)[65]) {
    int k0 = (tile & 7) * 64, n0 = (tile >> 3) * 64;
    int tx = threadIdx.x & 15, ty = threadIdx.x >> 4;
    #pragma unroll
    for (int i = 0; i < 4; ++i) {
        int k = i * 16 + ty;
        float4 v = *(const float4*)&W[(size_t)(k0 + k) * DIM + n0 + tx * 4];
        ts[k][tx * 4 + 0] = v.x; ts[k][tx * 4 + 1] = v.y;
        ts[k][tx * 4 + 2] = v.z; ts[k][tx * 4 + 3] = v.w;
    }
    __syncthreads();
    #pragma unroll
    for (int i = 0; i < 4; ++i) {
        int n = i * 16 + ty;
        ushort4 o;
        o.x = f2bf(ts[tx * 4 + 0][n]); o.y = f2bf(ts[tx * 4 + 1][n]);
        o.z = f2bf(ts[tx * 4 + 2][n]); o.w = f2bf(ts[tx * 4 + 3][n]);
        *(ushort4*)&WT[(size_t)(n0 + n) * DIM + k0 + tx * 4] = o;
    }
}

__global__ __launch_bounds__(256)
void prep_kernel(const float* __restrict__ H, const float* __restrict__ W1,
                 const float* __restrict__ W2, unsigned short* __restrict__ Abf,
                 unsigned short* __restrict__ WT1, unsigned short* __restrict__ WT2,
                 uint32_t* __restrict__ mask, int* __restrict__ cnt) {
    __shared__ float ts[64][65];
    int b = blockIdx.x;
    if (b < CONV_BLKS) {
        int i = b * 256 + threadIdx.x;           // one float4 per thread
        float4 v = ((const float4*)H)[i];
        ushort4 o;
        o.x = f2bf(v.x); o.y = f2bf(v.y); o.z = f2bf(v.z); o.w = f2bf(v.w);
        ((ushort4*)Abf)[i] = o;
    } else if (b < CONV_BLKS + TR_BLKS) {
        transpose_tile(W1, WT1, b - CONV_BLKS, ts);
    } else if (b < CONV_BLKS + 2 * TR_BLKS) {
        transpose_tile(W2, WT2, b - CONV_BLKS - TR_BLKS, ts);
    } else if (b < CONV_BLKS + 2 * TR_BLKS + MASK_BLKS) {
        int w = (b - CONV_BLKS - 2 * TR_BLKS) * 256 + threadIdx.x;  // one uint32 word
        uint32_t base = (uint32_t)w * 32;
        uint32_t m = 0;
        #pragma unroll
        for (int j = 0; j < 32; ++j) {
            uint32_t o0, o1;
            threefry_42(0u, base + j, o0, o1);
            uint32_t bits = o0 ^ o1;             // keep iff MSB clear (u < 0.5)
            m |= (uint32_t)(((int)bits >= 0) ? 1u : 0u) << j;
        }
        mask[w] = m;
    } else {
        int i = (b - CONV_BLKS - 2 * TR_BLKS - MASK_BLKS) * 1024 + threadIdx.x * 4;
        #pragma unroll
        for (int j = 0; j < 4; ++j)
            if (i + j < N_NODES) cnt[i + j] = 0;
    }
}

// ---------------- CSR build ----------------
__global__ void hist_kernel(const int* __restrict__ rows, int* __restrict__ cnt) {
    int e = blockIdx.x * blockDim.x + threadIdx.x;
    if (e < N_EDGES) atomicAdd(&cnt[rows[e]], 1);
}

__global__ __launch_bounds__(1024)
void scan_kernel(const int* __restrict__ cnt, int* __restrict__ rs, int* __restrict__ cur) {
    __shared__ int s[1024];
    int t = threadIdx.x;
    int base_i = t * 10;
    int local[10];
    int p = 0;
    if (t < 1000) {
        #pragma unroll
        for (int j = 0; j < 10; ++j) { local[j] = cnt[base_i + j]; p += local[j]; }
    }
    s[t] = p;
    __syncthreads();
    for (int off = 1; off < 1024; off <<= 1) {
        int v = (t >= off) ? s[t - off] : 0;
        __syncthreads();
        s[t] += v;
        __syncthreads();
    }
    if (t < 1000) {
        int run = s[t] - p;
        #pragma unroll
        for (int j = 0; j < 10; ++j) {
            rs[base_i + j]  = run;
            cur[base_i + j] = run;
            run += local[j];
        }
        if (t == 999) rs[N_NODES] = run;
    }
}

__global__ void scatter_kernel(const int* __restrict__ rows, const int* __restrict__ cols,
                               const float* __restrict__ vals, int* __restrict__ cur,
                               int* __restrict__ scol, float* __restrict__ sval) {
    int e = blockIdx.x * blockDim.x + threadIdx.x;
    if (e < N_EDGES) {
        int r = rows[e];
        int p = atomicAdd(&cur[r], 1);
        scol[p] = cols[e];
        sval[p] = vals[e];
    }
}

// ---------------- bf16 MFMA GEMM: C[M][512] = A[M][512] @ WT[n][k]^T ----------------
// 128x128 tile (r3 config), BK=64, 256 threads = 4 waves (2x2), each wave 64x64.
// LDS [row][8 slots of 16B], slot XOR-swizzled by (row&7); linear LDS dest for
// global_load_lds + inverse-swizzled GLOBAL source (rule #21, involution).
__global__ __launch_bounds__(256)
void mfma_gemm(const unsigned short* __restrict__ A, const unsigned short* __restrict__ BT,
               unsigned short* __restrict__ C, int M) {
    __shared__ short8 As[1024];   // 128 rows x 8 slots
    __shared__ short8 Bs[1024];
    int tid  = threadIdx.x;
    int wid  = tid >> 6, lane = tid & 63;
    int bm   = blockIdx.x * 128;
    int bn   = blockIdx.y * 128;
    int wm   = (wid >> 1) * 64, wn = (wid & 1) * 64;

    f32x4 acc[4][4] = {};

    int srow = lane >> 3;
    int sslot = lane & 7;

    for (int k0 = 0; k0 < DIM; k0 += 64) {
        #pragma unroll
        for (int c = 0; c < 4; ++c) {
            int chunk = wid * 4 + c;            // 16 chunks x 8 rows = 128 rows
            int r  = chunk * 8 + srow;
            int ks = sslot ^ (r & 7);           // inverse-swizzled source slot
            const unsigned short* ga = A  + (size_t)(bm + r) * DIM + k0 + ks * 8;
            const unsigned short* gb = BT + (size_t)(bn + r) * DIM + k0 + ks * 8;
            __builtin_amdgcn_global_load_lds(
                (const __attribute__((address_space(1))) void*)ga,
                (__attribute__((address_space(3))) void*)&As[chunk * 64], 16, 0, 0);
            __builtin_amdgcn_global_load_lds(
                (const __attribute__((address_space(1))) void*)gb,
                (__attribute__((address_space(3))) void*)&Bs[chunk * 64], 16, 0, 0);
        }
        __syncthreads();

        int lrow = lane & 15;
        int kgrp = lane >> 4;
        #pragma unroll
        for (int ks = 0; ks < 2; ++ks) {
            short8 af[4], bfr[4];
            #pragma unroll
            for (int i = 0; i < 4; ++i) {
                int r = wm + i * 16 + lrow;
                af[i]  = As[r * 8 + ((ks * 4 + kgrp) ^ (r & 7))];
                int n = wn + i * 16 + lrow;
                bfr[i] = Bs[n * 8 + ((ks * 4 + kgrp) ^ (n & 7))];
            }
            #pragma unroll
            for (int i = 0; i < 4; ++i)
                #pragma unroll
                for (int j = 0; j < 4; ++j)
                    acc[i][j] = __builtin_amdgcn_mfma_f32_16x16x32_bf16(
                        __builtin_bit_cast(bf16x8, af[i]),
                        __builtin_bit_cast(bf16x8, bfr[j]), acc[i][j], 0, 0, 0);
        }
        __syncthreads();
    }

    // C/D layout: col=lane&15, row=(lane>>4)*4+reg  [m89]
    int crow = (lane >> 4) * 4;
    int ccol = lane & 15;
    #pragma unroll
    for (int i = 0; i < 4; ++i) {
        #pragma unroll
        for (int r = 0; r < 4; ++r) {
            int row = bm + wm + i * 16 + crow + r;
            if (row < M) {
                size_t base = (size_t)row * DIM + bn + wn + ccol;
                #pragma unroll
                for (int j = 0; j < 4; ++j)
                    C[base + j * 16] = f2bf(acc[i][j][r]);
            }
        }
    }
}

// ---------------- SpMM: 1 block (128 thr) per row, thread owns 4 cols, 4-deep unroll ----
__global__ __launch_bounds__(128)
void spmm1_kernel(const unsigned short* __restrict__ X, const int* __restrict__ rs,
                  const int* __restrict__ scol, const float* __restrict__ sval,
                  const float* __restrict__ bias, const uint32_t* __restrict__ mask,
                  unsigned short* __restrict__ hout) {
    int row = blockIdx.x;
    int t = threadIdx.x;
    int start = rs[row], end = rs[row + 1];
    const ushort4* X4 = (const ushort4*)X;       // row stride = 128 ushort4
    float a0 = 0.f, a1 = 0.f, a2 = 0.f, a3 = 0.f;
    float c0 = 0.f, c1 = 0.f, c2 = 0.f, c3 = 0.f;
    int p = start;
    for (; p + 3 < end; p += 4) {
        int   i0 = scol[p],     i1 = scol[p + 1], i2 = scol[p + 2], i3 = scol[p + 3];
        float v0 = sval[p],     v1 = sval[p + 1], v2 = sval[p + 2], v3 = sval[p + 3];
        ushort4 x0 = X4[(size_t)i0 * 128 + t];
        ushort4 x1 = X4[(size_t)i1 * 128 + t];
        ushort4 x2 = X4[(size_t)i2 * 128 + t];
        ushort4 x3 = X4[(size_t)i3 * 128 + t];
        a0 = fmaf(v0, b2f(x0.x), a0); a1 = fmaf(v0, b2f(x0.y), a1);
        a2 = fmaf(v0, b2f(x0.z), a2); a3 = fmaf(v0, b2f(x0.w), a3);
        c0 = fmaf(v1, b2f(x1.x), c0); c1 = fmaf(v1, b2f(x1.y), c1);
        c2 = fmaf(v1, b2f(x1.z), c2); c3 = fmaf(v1, b2f(x1.w), c3);
        a0 = fmaf(v2, b2f(x2.x), a0); a1 = fmaf(v2, b2f(x2.y), a1);
        a2 = fmaf(v2, b2f(x2.z), a2); a3 = fmaf(v2, b2f(x2.w), a3);
        c0 = fmaf(v3, b2f(x3.x), c0); c1 = fmaf(v3, b2f(x3.y), c1);
        c2 = fmaf(v3, b2f(x3.z), c2); c3 = fmaf(v3, b2f(x3.w), c3);
    }
    for (; p < end; ++p) {
        int i0 = scol[p]; float v0 = sval[p];
        ushort4 x0 = X4[(size_t)i0 * 128 + t];
        a0 = fmaf(v0, b2f(x0.x), a0); a1 = fmaf(v0, b2f(x0.y), a1);
        a2 = fmaf(v0, b2f(x0.z), a2); a3 = fmaf(v0, b2f(x0.w), a3);
    }
    float r[4];
    float4 b = *(const float4*)&bias[t * 4];
    r[0] = a0 + c0 + b.x; r[1] = a1 + c1 + b.y;
    r[2] = a2 + c2 + b.z; r[3] = a3 + c3 + b.w;
    // dropout mask: bit (t*4+j)&31 of word [row*16 + t/8]
    uint32_t w = mask[(size_t)row * 16 + (t >> 3)];
    uint32_t nib = (w >> ((t & 7) * 4)) & 0xFu;
    ushort4 o;
    #pragma unroll
    for (int j = 0; j < 4; ++j) {
        float v = r[j];
        v = (v >= 0.f) ? v : NEG_SLOPE * v;
        r[j] = ((nib >> j) & 1u) ? v * 2.0f : 0.0f;
    }
    o.x = f2bf(r[0]); o.y = f2bf(r[1]); o.z = f2bf(r[2]); o.w = f2bf(r[3]);
    ((ushort4*)hout)[(size_t)row * 128 + t] = o;
}

__global__ __launch_bounds__(128)
void spmm2_kernel(const unsigned short* __restrict__ X, const int* __restrict__ rs,
                  const int* __restrict__ scol, const float* __restrict__ sval,
                  const float* __restrict__ bias, float* __restrict__ out) {
    int row = blockIdx.x;
    int t = threadIdx.x;
    int start = rs[row], end = rs[row + 1];
    const ushort4* X4 = (const ushort4*)X;
    float a0 = 0.f, a1 = 0.f, a2 = 0.f, a3 = 0.f;
    float c0 = 0.f, c1 = 0.f, c2 = 0.f, c3 = 0.f;
    int p = start;
    for (; p + 3 < end; p += 4) {
        int   i0 = scol[p],     i1 = scol[p + 1], i2 = scol[p + 2], i3 = scol[p + 3];
        float v0 = sval[p],     v1 = sval[p + 1], v2 = sval[p + 2], v3 = sval[p + 3];
        ushort4 x0 = X4[(size_t)i0 * 128 + t];
        ushort4 x1 = X4[(size_t)i1 * 128 + t];
        ushort4 x2 = X4[(size_t)i2 * 128 + t];
        ushort4 x3 = X4[(size_t)i3 * 128 + t];
        a0 = fmaf(v0, b2f(x0.x), a0); a1 = fmaf(v0, b2f(x0.y), a1);
        a2 = fmaf(v0, b2f(x0.z), a2); a3 = fmaf(v0, b2f(x0.w), a3);
        c0 = fmaf(v1, b2f(x1.x), c0); c1 = fmaf(v1, b2f(x1.y), c1);
        c2 = fmaf(v1, b2f(x1.z), c2); c3 = fmaf(v1, b2f(x1.w), c3);
        a0 = fmaf(v2, b2f(x2.x), a0); a1 = fmaf(v2, b2f(x2.y), a1);
        a2 = fmaf(v2, b2f(x2.z), a2); a3 = fmaf(v2, b2f(x2.w), a3);
        c0 = fmaf(v3, b2f(x3.x), c0); c1 = fmaf(v3, b2f(x3.y), c1);
        c2 = fmaf(v3, b2f(x3.z), c2); c3 = fmaf(v3, b2f(x3.w), c3);
    }
    for (; p < end; ++p) {
        int i0 = scol[p]; float v0 = sval[p];
        ushort4 x0 = X4[(size_t)i0 * 128 + t];
        a0 = fmaf(v0, b2f(x0.x), a0); a1 = fmaf(v0, b2f(x0.y), a1);
        a2 = fmaf(v0, b2f(x0.z), a2); a3 = fmaf(v0, b2f(x0.w), a3);
    }
    float4 b = *(const float4*)&bias[t * 4];
    float4 r;
    r.x = a0 + c0 + b.x; r.y = a1 + c1 + b.y;
    r.z = a2 + c2 + b.z; r.w = a3 + c3 + b.w;
    r.x = (r.x >= 0.f) ? r.x : NEG_SLOPE * r.x;
    r.y = (r.y >= 0.f) ? r.y : NEG_SLOPE * r.y;
    r.z = (r.z >= 0.f) ? r.z : NEG_SLOPE * r.z;
    r.w = (r.w >= 0.f) ? r.w : NEG_SLOPE * r.w;
    ((float4*)out)[(size_t)row * 128 + t] = r;
}

// ---------------- launch ----------------
extern "C" void kernel_launch(void* const* d_in, const int* in_sizes, int n_in,
                              void* d_out, int out_size, void* d_ws, size_t ws_size,
                              hipStream_t stream) {
    const float* H    = (const float*)d_in[0];
    const int*   rows = (const int*)  d_in[1];
    const int*   cols = (const int*)  d_in[2];
    const float* vals = (const float*)d_in[3];
    const float* W1   = (const float*)d_in[4];
    const float* b1   = (const float*)d_in[5];
    const float* W2   = (const float*)d_in[6];
    const float* b2   = (const float*)d_in[7];
    float* out = (float*)d_out;

    char* ws = (char*)d_ws;
    size_t off = 0;
    auto alloc = [&](size_t bytes) -> void* {
        off = (off + 255) & ~(size_t)255;
        void* p = ws + off;
        off += bytes;
        return p;
    };
    int*      cnt  = (int*)     alloc((size_t)N_NODES * 4);
    int*      rs   = (int*)     alloc((size_t)(N_NODES + 1) * 4);
    int*      cur  = (int*)     alloc((size_t)N_NODES * 4);
    int*      scol = (int*)     alloc((size_t)N_EDGES * 4);
    float*    sval = (float*)   alloc((size_t)N_EDGES * 4);
    uint32_t* mask = (uint32_t*)alloc((size_t)N_ELEMS / 8);          // 640KB bit-mask
    unsigned short* WT1 = (unsigned short*)alloc((size_t)DIM * DIM * 2);
    unsigned short* WT2 = (unsigned short*)alloc((size_t)DIM * DIM * 2);
    unsigned short* Abf = (unsigned short*)alloc((size_t)M_PAD * DIM * 2);
    unsigned short* hbf = (unsigned short*)alloc((size_t)M_PAD * DIM * 2);
    unsigned short* Xbf = (unsigned short*)alloc((size_t)N_NODES * DIM * 2);

    int prep_blocks = CONV_BLKS + 2 * TR_BLKS + MASK_BLKS + ZERO_BLKS;
    prep_kernel<<<prep_blocks, 256, 0, stream>>>(H, W1, W2, Abf, WT1, WT2, mask, cnt);
    hist_kernel<<<(N_EDGES + 255) / 256, 256, 0, stream>>>(rows, cnt);
    scan_kernel<<<1, 1024, 0, stream>>>(cnt, rs, cur);
    scatter_kernel<<<(N_EDGES + 255) / 256, 256, 0, stream>>>(rows, cols, vals, cur, scol, sval);

    dim3 ggrid(M_PAD / 128, DIM / 128);
    mfma_gemm<<<ggrid, 256, 0, stream>>>(Abf, WT1, Xbf, N_NODES);
    spmm1_kernel<<<N_NODES, 128, 0, stream>>>(Xbf, rs, scol, sval, b1, mask, hbf);
    mfma_gemm<<<ggrid, 256, 0, stream>>>(hbf, WT2, Xbf, N_NODES);
    spmm2_kernel<<<N_NODES, 128, 0, stream>>>(Xbf, rs, scol, sval, b2, out);
}

// Round 6
// 133.987 us; speedup vs baseline: 1.0251x; 1.0114x over previous
//
#include <hip/hip_runtime.h>
#include <stdint.h>

#define N_NODES 10000
#define M_PAD   10112    // 79 * 128
#define N_EDGES 160000
#define DIM     512
#define N_ELEMS 5120000  // N_NODES*DIM
#define NEG_SLOPE 0.25f

typedef short          short8   __attribute__((ext_vector_type(8)));
typedef unsigned short ushort8v __attribute__((ext_vector_type(8)));
typedef __bf16         bf16x8   __attribute__((ext_vector_type(8)));
typedef float          f32x4    __attribute__((ext_vector_type(4)));

__device__ __forceinline__ unsigned short f2bf(float f) {   // RNE f32->bf16
    uint32_t u = __builtin_bit_cast(uint32_t, f);
    uint32_t r = (u + 0x7fffu + ((u >> 16) & 1u)) >> 16;
    return (unsigned short)r;
}
__device__ __forceinline__ float b2f(unsigned short u) {
    return __builtin_bit_cast(float, (uint32_t)u << 16);
}

// ---------------- threefry2x32-20, key = jax.random.key(42) = (0, 42) ----------------
__device__ __forceinline__ uint32_t rotl32(uint32_t x, uint32_t d) {
    return (x << d) | (x >> (32u - d));
}
__device__ __forceinline__ void threefry_42(uint32_t x0, uint32_t x1,
                                            uint32_t& o0, uint32_t& o1) {
    const uint32_t ks0 = 0u, ks1 = 42u, ks2 = 0x1BD11BDAu ^ 42u;
    x0 += ks0; x1 += ks1;
#define TF_R4(a,b,c,d) \
    x0 += x1; x1 = rotl32(x1,a); x1 ^= x0; \
    x0 += x1; x1 = rotl32(x1,b); x1 ^= x0; \
    x0 += x1; x1 = rotl32(x1,c); x1 ^= x0; \
    x0 += x1; x1 = rotl32(x1,d); x1 ^= x0;
    TF_R4(13,15,26,6);  x0 += ks1; x1 += ks2 + 1u;
    TF_R4(17,29,16,24); x0 += ks2; x1 += ks0 + 2u;
    TF_R4(13,15,26,6);  x0 += ks0; x1 += ks1 + 3u;
    TF_R4(17,29,16,24); x0 += ks1; x1 += ks2 + 4u;
    TF_R4(13,15,26,6);  x0 += ks2; x1 += ks0 + 5u;
#undef TF_R4
    o0 = x0; o1 = x1;
}

// ---------------- fused prep: convert H, transpose W1/W2, dropout mask, zero cnt --------
#define CONV_BLKS 5000
#define TR_BLKS   64
#define MASK_BLKS 625
#define ZERO_BLKS 10

__device__ __forceinline__ void transpose_tile(const float* __restrict__ W,
                                               unsigned short* __restrict__ WT,
                                               int tile, float (*ts)[65]) {
    int k0 = (tile & 7) * 64, n0 = (tile >> 3) * 64;
    int tx = threadIdx.x & 15, ty = threadIdx.x >> 4;
    #pragma unroll
    for (int i = 0; i < 4; ++i) {
        int k = i * 16 + ty;
        float4 v = *(const float4*)&W[(size_t)(k0 + k) * DIM + n0 + tx * 4];
        ts[k][tx * 4 + 0] = v.x; ts[k][tx * 4 + 1] = v.y;
        ts[k][tx * 4 + 2] = v.z; ts[k][tx * 4 + 3] = v.w;
    }
    __syncthreads();
    #pragma unroll
    for (int i = 0; i < 4; ++i) {
        int n = i * 16 + ty;
        ushort4 o;
        o.x = f2bf(ts[tx * 4 + 0][n]); o.y = f2bf(ts[tx * 4 + 1][n]);
        o.z = f2bf(ts[tx * 4 + 2][n]); o.w = f2bf(ts[tx * 4 + 3][n]);
        *(ushort4*)&WT[(size_t)(n0 + n) * DIM + k0 + tx * 4] = o;
    }
}

__global__ __launch_bounds__(256)
void prep_kernel(const float* __restrict__ H, const float* __restrict__ W1,
                 const float* __restrict__ W2, unsigned short* __restrict__ Abf,
                 unsigned short* __restrict__ WT1, unsigned short* __restrict__ WT2,
                 uint32_t* __restrict__ mask, int* __restrict__ cnt) {
    __shared__ float ts[64][65];
    int b = blockIdx.x;
    if (b < CONV_BLKS) {
        int i = b * 256 + threadIdx.x;
        float4 v = ((const float4*)H)[i];
        ushort4 o;
        o.x = f2bf(v.x); o.y = f2bf(v.y); o.z = f2bf(v.z); o.w = f2bf(v.w);
        ((ushort4*)Abf)[i] = o;
    } else if (b < CONV_BLKS + TR_BLKS) {
        transpose_tile(W1, WT1, b - CONV_BLKS, ts);
    } else if (b < CONV_BLKS + 2 * TR_BLKS) {
        transpose_tile(W2, WT2, b - CONV_BLKS - TR_BLKS, ts);
    } else if (b < CONV_BLKS + 2 * TR_BLKS + MASK_BLKS) {
        int w = (b - CONV_BLKS - 2 * TR_BLKS) * 256 + threadIdx.x;
        uint32_t base = (uint32_t)w * 32;
        uint32_t m = 0;
        #pragma unroll
        for (int j = 0; j < 32; ++j) {
            uint32_t o0, o1;
            threefry_42(0u, base + j, o0, o1);
            uint32_t bits = o0 ^ o1;             // keep iff MSB clear (u < 0.5)
            m |= (uint32_t)(((int)bits >= 0) ? 1u : 0u) << j;
        }
        mask[w] = m;
    } else {
        int i = (b - CONV_BLKS - 2 * TR_BLKS - MASK_BLKS) * 1024 + threadIdx.x * 4;
        #pragma unroll
        for (int j = 0; j < 4; ++j)
            if (i + j < N_NODES) cnt[i + j] = 0;
    }
}

// ---------------- CSR build ----------------
__global__ void hist_kernel(const int* __restrict__ rows, int* __restrict__ cnt) {
    int e = blockIdx.x * blockDim.x + threadIdx.x;
    if (e < N_EDGES) atomicAdd(&cnt[rows[e]], 1);
}

__global__ __launch_bounds__(1024)
void scan_kernel(const int* __restrict__ cnt, int* __restrict__ rs, int* __restrict__ cur) {
    __shared__ int s[1024];
    int t = threadIdx.x;
    int base_i = t * 10;
    int local[10];
    int p = 0;
    if (t < 1000) {
        #pragma unroll
        for (int j = 0; j < 10; ++j) { local[j] = cnt[base_i + j]; p += local[j]; }
    }
    s[t] = p;
    __syncthreads();
    for (int off = 1; off < 1024; off <<= 1) {
        int v = (t >= off) ? s[t - off] : 0;
        __syncthreads();
        s[t] += v;
        __syncthreads();
    }
    if (t < 1000) {
        int run = s[t] - p;
        #pragma unroll
        for (int j = 0; j < 10; ++j) {
            rs[base_i + j]  = run;
            cur[base_i + j] = run;
            run += local[j];
        }
        if (t == 999) rs[N_NODES] = run;
    }
}

// packs (col, val) pairs so spmm does ONE 8B load per edge (or 16B per 2 edges)
__global__ void scatter_kernel(const int* __restrict__ rows, const int* __restrict__ cols,
                               const float* __restrict__ vals, int* __restrict__ cur,
                               int2* __restrict__ epack) {
    int e = blockIdx.x * blockDim.x + threadIdx.x;
    if (e < N_EDGES) {
        int r = rows[e];
        int p = atomicAdd(&cur[r], 1);
        epack[p] = make_int2(cols[e], __float_as_int(vals[e]));
    }
}

// ---------------- bf16 MFMA GEMM (r3 config, unchanged): 128x128, BK=64 ----------------
__global__ __launch_bounds__(256)
void mfma_gemm(const unsigned short* __restrict__ A, const unsigned short* __restrict__ BT,
               unsigned short* __restrict__ C, int M) {
    __shared__ short8 As[1024];
    __shared__ short8 Bs[1024];
    int tid  = threadIdx.x;
    int wid  = tid >> 6, lane = tid & 63;
    int bm   = blockIdx.x * 128;
    int bn   = blockIdx.y * 128;
    int wm   = (wid >> 1) * 64, wn = (wid & 1) * 64;

    f32x4 acc[4][4] = {};
    int srow = lane >> 3;
    int sslot = lane & 7;

    for (int k0 = 0; k0 < DIM; k0 += 64) {
        #pragma unroll
        for (int c = 0; c < 4; ++c) {
            int chunk = wid * 4 + c;
            int r  = chunk * 8 + srow;
            int ks = sslot ^ (r & 7);
            const unsigned short* ga = A  + (size_t)(bm + r) * DIM + k0 + ks * 8;
            const unsigned short* gb = BT + (size_t)(bn + r) * DIM + k0 + ks * 8;
            __builtin_amdgcn_global_load_lds(
                (const __attribute__((address_space(1))) void*)ga,
                (__attribute__((address_space(3))) void*)&As[chunk * 64], 16, 0, 0);
            __builtin_amdgcn_global_load_lds(
                (const __attribute__((address_space(1))) void*)gb,
                (__attribute__((address_space(3))) void*)&Bs[chunk * 64], 16, 0, 0);
        }
        __syncthreads();

        int lrow = lane & 15;
        int kgrp = lane >> 4;
        #pragma unroll
        for (int ks = 0; ks < 2; ++ks) {
            short8 af[4], bfr[4];
            #pragma unroll
            for (int i = 0; i < 4; ++i) {
                int r = wm + i * 16 + lrow;
                af[i]  = As[r * 8 + ((ks * 4 + kgrp) ^ (r & 7))];
                int n = wn + i * 16 + lrow;
                bfr[i] = Bs[n * 8 + ((ks * 4 + kgrp) ^ (n & 7))];
            }
            #pragma unroll
            for (int i = 0; i < 4; ++i)
                #pragma unroll
                for (int j = 0; j < 4; ++j)
                    acc[i][j] = __builtin_amdgcn_mfma_f32_16x16x32_bf16(
                        __builtin_bit_cast(bf16x8, af[i]),
                        __builtin_bit_cast(bf16x8, bfr[j]), acc[i][j], 0, 0, 0);
        }
        __syncthreads();
    }

    int crow = (lane >> 4) * 4;
    int ccol = lane & 15;
    #pragma unroll
    for (int i = 0; i < 4; ++i) {
        #pragma unroll
        for (int r = 0; r < 4; ++r) {
            int row = bm + wm + i * 16 + crow + r;
            if (row < M) {
                size_t base = (size_t)row * DIM + bn + wn + ccol;
                #pragma unroll
                for (int j = 0; j < 4; ++j)
                    C[base + j * 16] = f2bf(acc[i][j][r]);
            }
        }
    }
}

// ---------------- SpMM v3: block=128 (2 waves) per row ----------------
// Lane owns ushort8 (16B): ONE wave gathers a full 1KB X row per edge in one VMEM op.
// Waves split edges even/odd; 4 gathers in flight per wave; LDS combine at the end.
// spmm1 applies bias+leaky+dropout-mask and writes bf16; spmm2 bias+leaky fp32.
template <int LAYER>
__global__ __launch_bounds__(128)
void spmm_kernel(const unsigned short* __restrict__ X, const int* __restrict__ rs,
                 const int2* __restrict__ epack, const float* __restrict__ bias,
                 const uint8_t* __restrict__ mask, void* __restrict__ outp) {
    __shared__ float part[DIM];
    int row  = blockIdx.x;
    int w    = threadIdx.x >> 6;     // wave 0/1
    int lane = threadIdx.x & 63;
    int start = rs[row], end = rs[row + 1];
    const ushort8v* X8 = (const ushort8v*)X;     // row stride = 64 ushort8

    float acc[8] = {};
    int p = start + w;
    // 4 edges per wave in flight (8 per block)
    for (; p + 6 < end; p += 8) {
        int2 e0 = epack[p];
        int2 e1 = epack[p + 2];
        int2 e2 = epack[p + 4];
        int2 e3 = epack[p + 6];
        ushort8v x0 = X8[(size_t)e0.x * 64 + lane];
        ushort8v x1 = X8[(size_t)e1.x * 64 + lane];
        ushort8v x2 = X8[(size_t)e2.x * 64 + lane];
        ushort8v x3 = X8[(size_t)e3.x * 64 + lane];
        float v0 = __int_as_float(e0.y), v1 = __int_as_float(e1.y);
        float v2 = __int_as_float(e2.y), v3 = __int_as_float(e3.y);
        #pragma unroll
        for (int j = 0; j < 8; ++j) {
            acc[j] = fmaf(v0, b2f(x0[j]), acc[j]);
            acc[j] = fmaf(v1, b2f(x1[j]), acc[j]);
            acc[j] = fmaf(v2, b2f(x2[j]), acc[j]);
            acc[j] = fmaf(v3, b2f(x3[j]), acc[j]);
        }
    }
    for (; p < end; p += 2) {
        int2 e0 = epack[p];
        ushort8v x0 = X8[(size_t)e0.x * 64 + lane];
        float v0 = __int_as_float(e0.y);
        #pragma unroll
        for (int j = 0; j < 8; ++j) acc[j] = fmaf(v0, b2f(x0[j]), acc[j]);
    }

    if (w == 0) {
        #pragma unroll
        for (int j = 0; j < 8; ++j) part[lane * 8 + j] = acc[j];
    }
    __syncthreads();
    if (w == 1) {
        float4 bi0 = ((const float4*)bias)[lane * 2];
        float4 bi1 = ((const float4*)bias)[lane * 2 + 1];
        float bb[8] = { bi0.x, bi0.y, bi0.z, bi0.w, bi1.x, bi1.y, bi1.z, bi1.w };
        float r[8];
        #pragma unroll
        for (int j = 0; j < 8; ++j) {
            float v = acc[j] + part[lane * 8 + j] + bb[j];
            r[j] = (v >= 0.f) ? v : NEG_SLOPE * v;
        }
        if (LAYER == 1) {
            uint32_t mb = mask[(size_t)row * 64 + lane];   // 8 mask bits for these cols
            ushort8v o;
            #pragma unroll
            for (int j = 0; j < 8; ++j) {
                float v = ((mb >> j) & 1u) ? r[j] * 2.0f : 0.0f;
                o[j] = f2bf(v);
            }
            ((ushort8v*)outp)[(size_t)row * 64 + lane] = o;
        } else {
            float4 o0 = make_float4(r[0], r[1], r[2], r[3]);
            float4 o1 = make_float4(r[4], r[5], r[6], r[7]);
            ((float4*)outp)[(size_t)row * 128 + lane * 2]     = o0;
            ((float4*)outp)[(size_t)row * 128 + lane * 2 + 1] = o1;
        }
    }
}

// ---------------- launch ----------------
extern "C" void kernel_launch(void* const* d_in, const int* in_sizes, int n_in,
                              void* d_out, int out_size, void* d_ws, size_t ws_size,
                              hipStream_t stream) {
    const float* H    = (const float*)d_in[0];
    const int*   rows = (const int*)  d_in[1];
    const int*   cols = (const int*)  d_in[2];
    const float* vals = (const float*)d_in[3];
    const float* W1   = (const float*)d_in[4];
    const float* b1   = (const float*)d_in[5];
    const float* W2   = (const float*)d_in[6];
    const float* b2   = (const float*)d_in[7];
    float* out = (float*)d_out;

    char* ws = (char*)d_ws;
    size_t off = 0;
    auto alloc = [&](size_t bytes) -> void* {
        off = (off + 255) & ~(size_t)255;
        void* p = ws + off;
        off += bytes;
        return p;
    };
    int*      cnt   = (int*)     alloc((size_t)N_NODES * 4);
    int*      rs    = (int*)     alloc((size_t)(N_NODES + 1) * 4);
    int*      cur   = (int*)     alloc((size_t)N_NODES * 4);
    int2*     epack = (int2*)    alloc((size_t)N_EDGES * 8);
    uint32_t* mask  = (uint32_t*)alloc((size_t)N_ELEMS / 8);          // 640KB bit-mask
    unsigned short* WT1 = (unsigned short*)alloc((size_t)DIM * DIM * 2);
    unsigned short* WT2 = (unsigned short*)alloc((size_t)DIM * DIM * 2);
    unsigned short* Abf = (unsigned short*)alloc((size_t)M_PAD * DIM * 2);
    unsigned short* hbf = (unsigned short*)alloc((size_t)M_PAD * DIM * 2);
    unsigned short* Xbf = (unsigned short*)alloc((size_t)N_NODES * DIM * 2);

    int prep_blocks = CONV_BLKS + 2 * TR_BLKS + MASK_BLKS + ZERO_BLKS;
    prep_kernel<<<prep_blocks, 256, 0, stream>>>(H, W1, W2, Abf, WT1, WT2, mask, cnt);
    hist_kernel<<<(N_EDGES + 255) / 256, 256, 0, stream>>>(rows, cnt);
    scan_kernel<<<1, 1024, 0, stream>>>(cnt, rs, cur);
    scatter_kernel<<<(N_EDGES + 255) / 256, 256, 0, stream>>>(rows, cols, vals, cur, epack);

    dim3 ggrid(M_PAD / 128, DIM / 128);
    mfma_gemm<<<ggrid, 256, 0, stream>>>(Abf, WT1, Xbf, N_NODES);
    spmm_kernel<1><<<N_NODES, 128, 0, stream>>>(Xbf, rs, epack, b1,
                                                (const uint8_t*)mask, hbf);
    mfma_gemm<<<ggrid, 256, 0, stream>>>(hbf, WT2, Xbf, N_NODES);
    spmm_kernel<2><<<N_NODES, 128, 0, stream>>>(Xbf, rs, epack, b2,
                                                (const uint8_t*)mask, out);
}

// Round 7
// 106.778 us; speedup vs baseline: 1.2863x; 1.2548x over previous
//
#include <hip/hip_runtime.h>
#include <stdint.h>

#define N_NODES 10000
#define M_PAD   10112    // 79 * 128
#define N_EDGES 160000
#define DIM     512
#define N_ELEMS 5120000  // N_NODES*DIM
#define NEG_SLOPE 0.25f
#define ELL_W   64       // max degree slack: E[deg]=16, P(deg>64) ~ 1e-19

typedef short          short8   __attribute__((ext_vector_type(8)));
typedef unsigned short ushort8v __attribute__((ext_vector_type(8)));
typedef __bf16         bf16x8   __attribute__((ext_vector_type(8)));
typedef float          f32x4    __attribute__((ext_vector_type(4)));

__device__ __forceinline__ unsigned short f2bf(float f) {   // RNE f32->bf16
    uint32_t u = __builtin_bit_cast(uint32_t, f);
    uint32_t r = (u + 0x7fffu + ((u >> 16) & 1u)) >> 16;
    return (unsigned short)r;
}
__device__ __forceinline__ float b2f(unsigned short u) {
    return __builtin_bit_cast(float, (uint32_t)u << 16);
}

// ---------------- threefry2x32-20, key = jax.random.key(42) = (0, 42) ----------------
__device__ __forceinline__ uint32_t rotl32(uint32_t x, uint32_t d) {
    return (x << d) | (x >> (32u - d));
}
__device__ __forceinline__ void threefry_42(uint32_t x0, uint32_t x1,
                                            uint32_t& o0, uint32_t& o1) {
    const uint32_t ks0 = 0u, ks1 = 42u, ks2 = 0x1BD11BDAu ^ 42u;
    x0 += ks0; x1 += ks1;
#define TF_R4(a,b,c,d) \
    x0 += x1; x1 = rotl32(x1,a); x1 ^= x0; \
    x0 += x1; x1 = rotl32(x1,b); x1 ^= x0; \
    x0 += x1; x1 = rotl32(x1,c); x1 ^= x0; \
    x0 += x1; x1 = rotl32(x1,d); x1 ^= x0;
    TF_R4(13,15,26,6);  x0 += ks1; x1 += ks2 + 1u;
    TF_R4(17,29,16,24); x0 += ks2; x1 += ks0 + 2u;
    TF_R4(13,15,26,6);  x0 += ks0; x1 += ks1 + 3u;
    TF_R4(17,29,16,24); x0 += ks1; x1 += ks2 + 4u;
    TF_R4(13,15,26,6);  x0 += ks2; x1 += ks0 + 5u;
#undef TF_R4
    o0 = x0; o1 = x1;
}

// ---------------- fused prep: convert H, transpose W1/W2, zero deg ----------------
#define CONV_BLKS 5000
#define TR_BLKS   64
#define ZERO_BLKS 10

__device__ __forceinline__ void transpose_tile(const float* __restrict__ W,
                                               unsigned short* __restrict__ WT,
                                               int tile, float (*ts)[65]) {
    int k0 = (tile & 7) * 64, n0 = (tile >> 3) * 64;
    int tx = threadIdx.x & 15, ty = threadIdx.x >> 4;
    #pragma unroll
    for (int i = 0; i < 4; ++i) {
        int k = i * 16 + ty;
        float4 v = *(const float4*)&W[(size_t)(k0 + k) * DIM + n0 + tx * 4];
        ts[k][tx * 4 + 0] = v.x; ts[k][tx * 4 + 1] = v.y;
        ts[k][tx * 4 + 2] = v.z; ts[k][tx * 4 + 3] = v.w;
    }
    __syncthreads();
    #pragma unroll
    for (int i = 0; i < 4; ++i) {
        int n = i * 16 + ty;
        ushort4 o;
        o.x = f2bf(ts[tx * 4 + 0][n]); o.y = f2bf(ts[tx * 4 + 1][n]);
        o.z = f2bf(ts[tx * 4 + 2][n]); o.w = f2bf(ts[tx * 4 + 3][n]);
        *(ushort4*)&WT[(size_t)(n0 + n) * DIM + k0 + tx * 4] = o;
    }
}

__global__ __launch_bounds__(256)
void prep_kernel(const float* __restrict__ H, const float* __restrict__ W1,
                 const float* __restrict__ W2, unsigned short* __restrict__ Abf,
                 unsigned short* __restrict__ WT1, unsigned short* __restrict__ WT2,
                 int* __restrict__ deg) {
    __shared__ float ts[64][65];
    int b = blockIdx.x;
    if (b < CONV_BLKS) {
        int i = b * 256 + threadIdx.x;
        float4 v = ((const float4*)H)[i];
        ushort4 o;
        o.x = f2bf(v.x); o.y = f2bf(v.y); o.z = f2bf(v.z); o.w = f2bf(v.w);
        ((ushort4*)Abf)[i] = o;
    } else if (b < CONV_BLKS + TR_BLKS) {
        transpose_tile(W1, WT1, b - CONV_BLKS, ts);
    } else if (b < CONV_BLKS + 2 * TR_BLKS) {
        transpose_tile(W2, WT2, b - CONV_BLKS - TR_BLKS, ts);
    } else {
        int i = (b - CONV_BLKS - 2 * TR_BLKS) * 1024 + threadIdx.x * 4;
        #pragma unroll
        for (int j = 0; j < 4; ++j)
            if (i + j < N_NODES) deg[i + j] = 0;
    }
}

// ---------------- ELL build: one kernel, no hist/scan ----------------
__global__ void ell_scatter(const int* __restrict__ rows, const int* __restrict__ cols,
                            const float* __restrict__ vals, int* __restrict__ deg,
                            int2* __restrict__ epack) {
    int e = blockIdx.x * blockDim.x + threadIdx.x;
    if (e < N_EDGES) {
        int r = rows[e];
        int p = atomicAdd(&deg[r], 1);
        epack[(size_t)r * ELL_W + p] = make_int2(cols[e], __float_as_int(vals[e]));
    }
}

// ---------------- bf16 MFMA GEMM (unchanged r3 config): 128x128, BK=64 ----------------
__global__ __launch_bounds__(256)
void mfma_gemm(const unsigned short* __restrict__ A, const unsigned short* __restrict__ BT,
               unsigned short* __restrict__ C, int M) {
    __shared__ short8 As[1024];
    __shared__ short8 Bs[1024];
    int tid  = threadIdx.x;
    int wid  = tid >> 6, lane = tid & 63;
    int bm   = blockIdx.x * 128;
    int bn   = blockIdx.y * 128;
    int wm   = (wid >> 1) * 64, wn = (wid & 1) * 64;

    f32x4 acc[4][4] = {};
    int srow = lane >> 3;
    int sslot = lane & 7;

    for (int k0 = 0; k0 < DIM; k0 += 64) {
        #pragma unroll
        for (int c = 0; c < 4; ++c) {
            int chunk = wid * 4 + c;
            int r  = chunk * 8 + srow;
            int ks = sslot ^ (r & 7);
            const unsigned short* ga = A  + (size_t)(bm + r) * DIM + k0 + ks * 8;
            const unsigned short* gb = BT + (size_t)(bn + r) * DIM + k0 + ks * 8;
            __builtin_amdgcn_global_load_lds(
                (const __attribute__((address_space(1))) void*)ga,
                (__attribute__((address_space(3))) void*)&As[chunk * 64], 16, 0, 0);
            __builtin_amdgcn_global_load_lds(
                (const __attribute__((address_space(1))) void*)gb,
                (__attribute__((address_space(3))) void*)&Bs[chunk * 64], 16, 0, 0);
        }
        __syncthreads();

        int lrow = lane & 15;
        int kgrp = lane >> 4;
        #pragma unroll
        for (int ks = 0; ks < 2; ++ks) {
            short8 af[4], bfr[4];
            #pragma unroll
            for (int i = 0; i < 4; ++i) {
                int r = wm + i * 16 + lrow;
                af[i]  = As[r * 8 + ((ks * 4 + kgrp) ^ (r & 7))];
                int n = wn + i * 16 + lrow;
                bfr[i] = Bs[n * 8 + ((ks * 4 + kgrp) ^ (n & 7))];
            }
            #pragma unroll
            for (int i = 0; i < 4; ++i)
                #pragma unroll
                for (int j = 0; j < 4; ++j)
                    acc[i][j] = __builtin_amdgcn_mfma_f32_16x16x32_bf16(
                        __builtin_bit_cast(bf16x8, af[i]),
                        __builtin_bit_cast(bf16x8, bfr[j]), acc[i][j], 0, 0, 0);
        }
        __syncthreads();
    }

    int crow = (lane >> 4) * 4;
    int ccol = lane & 15;
    #pragma unroll
    for (int i = 0; i < 4; ++i) {
        #pragma unroll
        for (int r = 0; r < 4; ++r) {
            int row = bm + wm + i * 16 + crow + r;
            if (row < M) {
                size_t base = (size_t)row * DIM + bn + wn + ccol;
                #pragma unroll
                for (int j = 0; j < 4; ++j)
                    C[base + j * 16] = f2bf(acc[i][j][r]);
            }
        }
    }
}

// ---------------- SpMM v4: block=128 (2 waves) per row, ELL edges ----------------
// Lane owns ushort8 (16B): one wave gathers a full 1KB X row per edge in one VMEM op.
// Waves take contiguous 8-edge chunks alternately; int4 loads pack 2 edges; 8 gathers
// in flight per wave. Transposed LDS partials (conflict-free); both waves do epilogue.
// LAYER 1: bias+leaky+inline-threefry-dropout -> bf16. LAYER 2: bias+leaky -> fp32.
template <int LAYER>
__global__ __launch_bounds__(128)
void spmm_kernel(const unsigned short* __restrict__ X, const int* __restrict__ deg,
                 const int2* __restrict__ epack, const float* __restrict__ bias,
                 void* __restrict__ outp) {
    __shared__ float part[2][DIM];
    int row  = blockIdx.x;
    int w    = threadIdx.x >> 6;
    int lane = threadIdx.x & 63;
    int d = deg[row];
    const int2* ep = epack + (size_t)row * ELL_W;
    const ushort8v* X8 = (const ushort8v*)X;     // row stride = 64 ushort8

    float acc[8] = {};
    int base = w * 8;
    for (; base + 8 <= d; base += 16) {          // full 8-edge chunk for this wave
        int4 e01 = *(const int4*)(ep + base);
        int4 e23 = *(const int4*)(ep + base + 2);
        int4 e45 = *(const int4*)(ep + base + 4);
        int4 e67 = *(const int4*)(ep + base + 6);
        ushort8v x0 = X8[(size_t)e01.x * 64 + lane];
        ushort8v x1 = X8[(size_t)e01.z * 64 + lane];
        ushort8v x2 = X8[(size_t)e23.x * 64 + lane];
        ushort8v x3 = X8[(size_t)e23.z * 64 + lane];
        ushort8v x4 = X8[(size_t)e45.x * 64 + lane];
        ushort8v x5 = X8[(size_t)e45.z * 64 + lane];
        ushort8v x6 = X8[(size_t)e67.x * 64 + lane];
        ushort8v x7 = X8[(size_t)e67.z * 64 + lane];
        float v0 = __int_as_float(e01.y), v1 = __int_as_float(e01.w);
        float v2 = __int_as_float(e23.y), v3 = __int_as_float(e23.w);
        float v4 = __int_as_float(e45.y), v5 = __int_as_float(e45.w);
        float v6 = __int_as_float(e67.y), v7 = __int_as_float(e67.w);
        #pragma unroll
        for (int j = 0; j < 8; ++j) {
            acc[j] = fmaf(v0, b2f(x0[j]), acc[j]);
            acc[j] = fmaf(v1, b2f(x1[j]), acc[j]);
            acc[j] = fmaf(v2, b2f(x2[j]), acc[j]);
            acc[j] = fmaf(v3, b2f(x3[j]), acc[j]);
            acc[j] = fmaf(v4, b2f(x4[j]), acc[j]);
            acc[j] = fmaf(v5, b2f(x5[j]), acc[j]);
            acc[j] = fmaf(v6, b2f(x6[j]), acc[j]);
            acc[j] = fmaf(v7, b2f(x7[j]), acc[j]);
        }
    }
    int tail_end = base + 8 < d ? base + 8 : d;  // partial tail chunk (this wave only)
    for (int s = base; s < tail_end; ++s) {
        int2 e = ep[s];
        ushort8v x = X8[(size_t)e.x * 64 + lane];
        float v = __int_as_float(e.y);
        #pragma unroll
        for (int j = 0; j < 8; ++j) acc[j] = fmaf(v, b2f(x[j]), acc[j]);
    }

    // transposed partials: lane l col l*8+j -> part[w][j*64+l]  (consecutive lanes =
    // consecutive banks, conflict-free)
    #pragma unroll
    for (int j = 0; j < 8; ++j) part[w][j * 64 + lane] = acc[j];
    __syncthreads();

    int t = threadIdx.x;                         // thread t owns cols 4t..4t+3
    float4 b = *(const float4*)&bias[t * 4];
    float bb[4] = { b.x, b.y, b.z, b.w };
    float r[4];
    #pragma unroll
    for (int j = 0; j < 4; ++j) {
        int c = t * 4 + j;
        int idx = (c & 7) * 64 + (c >> 3);       // read = 2 lanes/bank max (free)
        float v = part[0][idx] + part[1][idx] + bb[j];
        r[j] = (v >= 0.f) ? v : NEG_SLOPE * v;
    }
    if (LAYER == 1) {
        uint32_t e0 = (uint32_t)row * DIM + t * 4;
        ushort4 o;
        #pragma unroll
        for (int j = 0; j < 4; ++j) {
            uint32_t o0, o1;
            threefry_42(0u, e0 + j, o0, o1);     // partitionable: bits=o0^o1, keep iff MSB clear
            uint32_t bits = o0 ^ o1;
            float v = ((int)bits >= 0) ? r[j] * 2.0f : 0.0f;
            ((unsigned short*)&o)[j] = f2bf(v);
        }
        ((ushort4*)outp)[(size_t)row * 128 + t] = o;
    } else {
        float4 o = make_float4(r[0], r[1], r[2], r[3]);
        ((float4*)outp)[(size_t)row * 128 + t] = o;
    }
}

// ---------------- launch ----------------
extern "C" void kernel_launch(void* const* d_in, const int* in_sizes, int n_in,
                              void* d_out, int out_size, void* d_ws, size_t ws_size,
                              hipStream_t stream) {
    const float* H    = (const float*)d_in[0];
    const int*   rows = (const int*)  d_in[1];
    const int*   cols = (const int*)  d_in[2];
    const float* vals = (const float*)d_in[3];
    const float* W1   = (const float*)d_in[4];
    const float* b1   = (const float*)d_in[5];
    const float* W2   = (const float*)d_in[6];
    const float* b2   = (const float*)d_in[7];
    float* out = (float*)d_out;

    char* ws = (char*)d_ws;
    size_t off = 0;
    auto alloc = [&](size_t bytes) -> void* {
        off = (off + 255) & ~(size_t)255;
        void* p = ws + off;
        off += bytes;
        return p;
    };
    int*  deg   = (int*) alloc((size_t)N_NODES * 4);
    int2* epack = (int2*)alloc((size_t)N_NODES * ELL_W * 8);   // 5.12 MB ELL
    unsigned short* WT1 = (unsigned short*)alloc((size_t)DIM * DIM * 2);
    unsigned short* WT2 = (unsigned short*)alloc((size_t)DIM * DIM * 2);
    unsigned short* Abf = (unsigned short*)alloc((size_t)M_PAD * DIM * 2);
    unsigned short* hbf = (unsigned short*)alloc((size_t)M_PAD * DIM * 2);
    unsigned short* Xbf = (unsigned short*)alloc((size_t)N_NODES * DIM * 2);

    int prep_blocks = CONV_BLKS + 2 * TR_BLKS + ZERO_BLKS;
    prep_kernel<<<prep_blocks, 256, 0, stream>>>(H, W1, W2, Abf, WT1, WT2, deg);
    ell_scatter<<<(N_EDGES + 255) / 256, 256, 0, stream>>>(rows, cols, vals, deg, epack);

    dim3 ggrid(M_PAD / 128, DIM / 128);
    mfma_gemm<<<ggrid, 256, 0, stream>>>(Abf, WT1, Xbf, N_NODES);
    spmm_kernel<1><<<N_NODES, 128, 0, stream>>>(Xbf, deg, epack, b1, hbf);
    mfma_gemm<<<ggrid, 256, 0, stream>>>(hbf, WT2, Xbf, N_NODES);
    spmm_kernel<2><<<N_NODES, 128, 0, stream>>>(Xbf, deg, epack, b2, out);
}

// Round 8
// 102.168 us; speedup vs baseline: 1.3444x; 1.0451x over previous
//
#include <hip/hip_runtime.h>
#include <stdint.h>

#define N_NODES 10000
#define M_PAD   10112    // 79 * 128
#define N_EDGES 160000
#define DIM     512
#define N_ELEMS 5120000  // N_NODES*DIM
#define NEG_SLOPE 0.25f
#define ELL_W   64       // max degree slack: E[deg]=16, P(deg>64) ~ 1e-19

typedef short          short8   __attribute__((ext_vector_type(8)));
typedef unsigned short ushort8v __attribute__((ext_vector_type(8)));
typedef __bf16         bf16x8   __attribute__((ext_vector_type(8)));
typedef float          f32x4    __attribute__((ext_vector_type(4)));

__device__ __forceinline__ unsigned short f2bf(float f) {   // RNE f32->bf16
    uint32_t u = __builtin_bit_cast(uint32_t, f);
    uint32_t r = (u + 0x7fffu + ((u >> 16) & 1u)) >> 16;
    return (unsigned short)r;
}
__device__ __forceinline__ float b2f(unsigned short u) {
    return __builtin_bit_cast(float, (uint32_t)u << 16);
}

// ---------------- threefry2x32-20, key = jax.random.key(42) = (0, 42) ----------------
__device__ __forceinline__ uint32_t rotl32(uint32_t x, uint32_t d) {
    return (x << d) | (x >> (32u - d));
}
__device__ __forceinline__ void threefry_42(uint32_t x0, uint32_t x1,
                                            uint32_t& o0, uint32_t& o1) {
    const uint32_t ks0 = 0u, ks1 = 42u, ks2 = 0x1BD11BDAu ^ 42u;
    x0 += ks0; x1 += ks1;
#define TF_R4(a,b,c,d) \
    x0 += x1; x1 = rotl32(x1,a); x1 ^= x0; \
    x0 += x1; x1 = rotl32(x1,b); x1 ^= x0; \
    x0 += x1; x1 = rotl32(x1,c); x1 ^= x0; \
    x0 += x1; x1 = rotl32(x1,d); x1 ^= x0;
    TF_R4(13,15,26,6);  x0 += ks1; x1 += ks2 + 1u;
    TF_R4(17,29,16,24); x0 += ks2; x1 += ks0 + 2u;
    TF_R4(13,15,26,6);  x0 += ks0; x1 += ks1 + 3u;
    TF_R4(17,29,16,24); x0 += ks1; x1 += ks2 + 4u;
    TF_R4(13,15,26,6);  x0 += ks2; x1 += ks0 + 5u;
#undef TF_R4
    o0 = x0; o1 = x1;
}

// ------- fused prep: convert H, transpose W1/W2, zero epack (ELL pads), zero deg -------
#define CONV_BLKS 5000
#define TR_BLKS   64
#define EZ_BLKS   1250   // 10000*64 edge slots * 8B / (256 thr * 16B)
#define ZERO_BLKS 10

__device__ __forceinline__ void transpose_tile(const float* __restrict__ W,
                                               unsigned short* __restrict__ WT,
                                               int tile, float (*ts)[65]) {
    int k0 = (tile & 7) * 64, n0 = (tile >> 3) * 64;
    int tx = threadIdx.x & 15, ty = threadIdx.x >> 4;
    #pragma unroll
    for (int i = 0; i < 4; ++i) {
        int k = i * 16 + ty;
        float4 v = *(const float4*)&W[(size_t)(k0 + k) * DIM + n0 + tx * 4];
        ts[k][tx * 4 + 0] = v.x; ts[k][tx * 4 + 1] = v.y;
        ts[k][tx * 4 + 2] = v.z; ts[k][tx * 4 + 3] = v.w;
    }
    __syncthreads();
    #pragma unroll
    for (int i = 0; i < 4; ++i) {
        int n = i * 16 + ty;
        ushort4 o;
        o.x = f2bf(ts[tx * 4 + 0][n]); o.y = f2bf(ts[tx * 4 + 1][n]);
        o.z = f2bf(ts[tx * 4 + 2][n]); o.w = f2bf(ts[tx * 4 + 3][n]);
        *(ushort4*)&WT[(size_t)(n0 + n) * DIM + k0 + tx * 4] = o;
    }
}

__global__ __launch_bounds__(256)
void prep_kernel(const float* __restrict__ H, const float* __restrict__ W1,
                 const float* __restrict__ W2, unsigned short* __restrict__ Abf,
                 unsigned short* __restrict__ WT1, unsigned short* __restrict__ WT2,
                 int4* __restrict__ epack4, int* __restrict__ deg) {
    __shared__ float ts[64][65];
    int b = blockIdx.x;
    if (b < CONV_BLKS) {
        int i = b * 256 + threadIdx.x;
        float4 v = ((const float4*)H)[i];
        ushort4 o;
        o.x = f2bf(v.x); o.y = f2bf(v.y); o.z = f2bf(v.z); o.w = f2bf(v.w);
        ((ushort4*)Abf)[i] = o;
    } else if (b < CONV_BLKS + TR_BLKS) {
        transpose_tile(W1, WT1, b - CONV_BLKS, ts);
    } else if (b < CONV_BLKS + 2 * TR_BLKS) {
        transpose_tile(W2, WT2, b - CONV_BLKS - TR_BLKS, ts);
    } else if (b < CONV_BLKS + 2 * TR_BLKS + EZ_BLKS) {
        int i = (b - CONV_BLKS - 2 * TR_BLKS) * 256 + threadIdx.x;
        epack4[i] = make_int4(0, 0, 0, 0);       // pad edges: col 0, val 0.0
    } else {
        int i = (b - CONV_BLKS - 2 * TR_BLKS - EZ_BLKS) * 1024 + threadIdx.x * 4;
        #pragma unroll
        for (int j = 0; j < 4; ++j)
            if (i + j < N_NODES) deg[i + j] = 0;
    }
}

// ---------------- ELL build ----------------
__global__ void ell_scatter(const int* __restrict__ rows, const int* __restrict__ cols,
                            const float* __restrict__ vals, int* __restrict__ deg,
                            int2* __restrict__ epack) {
    int e = blockIdx.x * blockDim.x + threadIdx.x;
    if (e < N_EDGES) {
        int r = rows[e];
        int p = atomicAdd(&deg[r], 1);
        epack[(size_t)r * ELL_W + p] = make_int2(cols[e], __float_as_int(vals[e]));
    }
}

// ---------------- bf16 MFMA GEMM (unchanged r3 config): 128x128, BK=64 ----------------
__global__ __launch_bounds__(256)
void mfma_gemm(const unsigned short* __restrict__ A, const unsigned short* __restrict__ BT,
               unsigned short* __restrict__ C, int M) {
    __shared__ short8 As[1024];
    __shared__ short8 Bs[1024];
    int tid  = threadIdx.x;
    int wid  = tid >> 6, lane = tid & 63;
    int bm   = blockIdx.x * 128;
    int bn   = blockIdx.y * 128;
    int wm   = (wid >> 1) * 64, wn = (wid & 1) * 64;

    f32x4 acc[4][4] = {};
    int srow = lane >> 3;
    int sslot = lane & 7;

    for (int k0 = 0; k0 < DIM; k0 += 64) {
        #pragma unroll
        for (int c = 0; c < 4; ++c) {
            int chunk = wid * 4 + c;
            int r  = chunk * 8 + srow;
            int ks = sslot ^ (r & 7);
            const unsigned short* ga = A  + (size_t)(bm + r) * DIM + k0 + ks * 8;
            const unsigned short* gb = BT + (size_t)(bn + r) * DIM + k0 + ks * 8;
            __builtin_amdgcn_global_load_lds(
                (const __attribute__((address_space(1))) void*)ga,
                (__attribute__((address_space(3))) void*)&As[chunk * 64], 16, 0, 0);
            __builtin_amdgcn_global_load_lds(
                (const __attribute__((address_space(1))) void*)gb,
                (__attribute__((address_space(3))) void*)&Bs[chunk * 64], 16, 0, 0);
        }
        __syncthreads();

        int lrow = lane & 15;
        int kgrp = lane >> 4;
        #pragma unroll
        for (int ks = 0; ks < 2; ++ks) {
            short8 af[4], bfr[4];
            #pragma unroll
            for (int i = 0; i < 4; ++i) {
                int r = wm + i * 16 + lrow;
                af[i]  = As[r * 8 + ((ks * 4 + kgrp) ^ (r & 7))];
                int n = wn + i * 16 + lrow;
                bfr[i] = Bs[n * 8 + ((ks * 4 + kgrp) ^ (n & 7))];
            }
            #pragma unroll
            for (int i = 0; i < 4; ++i)
                #pragma unroll
                for (int j = 0; j < 4; ++j)
                    acc[i][j] = __builtin_amdgcn_mfma_f32_16x16x32_bf16(
                        __builtin_bit_cast(bf16x8, af[i]),
                        __builtin_bit_cast(bf16x8, bfr[j]), acc[i][j], 0, 0, 0);
        }
        __syncthreads();
    }

    int crow = (lane >> 4) * 4;
    int ccol = lane & 15;
    #pragma unroll
    for (int i = 0; i < 4; ++i) {
        #pragma unroll
        for (int r = 0; r < 4; ++r) {
            int row = bm + wm + i * 16 + crow + r;
            if (row < M) {
                size_t base = (size_t)row * DIM + bn + wn + ccol;
                #pragma unroll
                for (int j = 0; j < 4; ++j)
                    C[base + j * 16] = f2bf(acc[i][j][r]);
            }
        }
    }
}

// ---------------- SpMM v5: ONE WAVE PER ROW, 16 gathers in flight, no LDS ----------------
// Lane owns ushort8 (cols lane*8..lane*8+7). ELL rows padded to a multiple of 8 with
// (0, 0.0) edges (exact: fma with v=0; X row 0 re-reads are L1-hits). Block = 4 rows.
template <int LAYER>
__global__ __launch_bounds__(256)
void spmm_kernel(const unsigned short* __restrict__ X, const int* __restrict__ deg,
                 const int2* __restrict__ epack, const float* __restrict__ bias,
                 void* __restrict__ outp) {
    int row  = blockIdx.x * 4 + (threadIdx.x >> 6);
    int lane = threadIdx.x & 63;
    int d  = deg[row];
    int dp = (d + 7) & ~7;                       // padded degree (pads are zero edges)
    const int2* ep = epack + (size_t)row * ELL_W;
    const ushort8v* X8 = (const ushort8v*)X;     // row stride = 64 ushort8

    float acc[8] = {};
    int base = 0;
    for (; base + 16 <= dp; base += 16) {        // 16 gathers in flight
        int4 eA = *(const int4*)(ep + base);
        int4 eB = *(const int4*)(ep + base + 2);
        int4 eC = *(const int4*)(ep + base + 4);
        int4 eD = *(const int4*)(ep + base + 6);
        int4 eE = *(const int4*)(ep + base + 8);
        int4 eF = *(const int4*)(ep + base + 10);
        int4 eG = *(const int4*)(ep + base + 12);
        int4 eH = *(const int4*)(ep + base + 14);
        ushort8v x0 = X8[(size_t)eA.x * 64 + lane];
        ushort8v x1 = X8[(size_t)eA.z * 64 + lane];
        ushort8v x2 = X8[(size_t)eB.x * 64 + lane];
        ushort8v x3 = X8[(size_t)eB.z * 64 + lane];
        ushort8v x4 = X8[(size_t)eC.x * 64 + lane];
        ushort8v x5 = X8[(size_t)eC.z * 64 + lane];
        ushort8v x6 = X8[(size_t)eD.x * 64 + lane];
        ushort8v x7 = X8[(size_t)eD.z * 64 + lane];
        ushort8v x8 = X8[(size_t)eE.x * 64 + lane];
        ushort8v x9 = X8[(size_t)eE.z * 64 + lane];
        ushort8v xa = X8[(size_t)eF.x * 64 + lane];
        ushort8v xb = X8[(size_t)eF.z * 64 + lane];
        ushort8v xc = X8[(size_t)eG.x * 64 + lane];
        ushort8v xd = X8[(size_t)eG.z * 64 + lane];
        ushort8v xe = X8[(size_t)eH.x * 64 + lane];
        ushort8v xf = X8[(size_t)eH.z * 64 + lane];
        float v0 = __int_as_float(eA.y), v1 = __int_as_float(eA.w);
        float v2 = __int_as_float(eB.y), v3 = __int_as_float(eB.w);
        float v4 = __int_as_float(eC.y), v5 = __int_as_float(eC.w);
        float v6 = __int_as_float(eD.y), v7 = __int_as_float(eD.w);
        float v8 = __int_as_float(eE.y), v9 = __int_as_float(eE.w);
        float va = __int_as_float(eF.y), vb = __int_as_float(eF.w);
        float vc = __int_as_float(eG.y), vd = __int_as_float(eG.w);
        float ve = __int_as_float(eH.y), vf = __int_as_float(eH.w);
        #pragma unroll
        for (int j = 0; j < 8; ++j) {
            acc[j] = fmaf(v0, b2f(x0[j]), acc[j]);
            acc[j] = fmaf(v1, b2f(x1[j]), acc[j]);
            acc[j] = fmaf(v2, b2f(x2[j]), acc[j]);
            acc[j] = fmaf(v3, b2f(x3[j]), acc[j]);
            acc[j] = fmaf(v4, b2f(x4[j]), acc[j]);
            acc[j] = fmaf(v5, b2f(x5[j]), acc[j]);
            acc[j] = fmaf(v6, b2f(x6[j]), acc[j]);
            acc[j] = fmaf(v7, b2f(x7[j]), acc[j]);
            acc[j] = fmaf(v8, b2f(x8[j]), acc[j]);
            acc[j] = fmaf(v9, b2f(x9[j]), acc[j]);
            acc[j] = fmaf(va, b2f(xa[j]), acc[j]);
            acc[j] = fmaf(vb, b2f(xb[j]), acc[j]);
            acc[j] = fmaf(vc, b2f(xc[j]), acc[j]);
            acc[j] = fmaf(vd, b2f(xd[j]), acc[j]);
            acc[j] = fmaf(ve, b2f(xe[j]), acc[j]);
            acc[j] = fmaf(vf, b2f(xf[j]), acc[j]);
        }
    }
    if (base < dp) {                             // exactly one 8-edge chunk
        int4 eA = *(const int4*)(ep + base);
        int4 eB = *(const int4*)(ep + base + 2);
        int4 eC = *(const int4*)(ep + base + 4);
        int4 eD = *(const int4*)(ep + base + 6);
        ushort8v x0 = X8[(size_t)eA.x * 64 + lane];
        ushort8v x1 = X8[(size_t)eA.z * 64 + lane];
        ushort8v x2 = X8[(size_t)eB.x * 64 + lane];
        ushort8v x3 = X8[(size_t)eB.z * 64 + lane];
        ushort8v x4 = X8[(size_t)eC.x * 64 + lane];
        ushort8v x5 = X8[(size_t)eC.z * 64 + lane];
        ushort8v x6 = X8[(size_t)eD.x * 64 + lane];
        ushort8v x7 = X8[(size_t)eD.z * 64 + lane];
        float v0 = __int_as_float(eA.y), v1 = __int_as_float(eA.w);
        float v2 = __int_as_float(eB.y), v3 = __int_as_float(eB.w);
        float v4 = __int_as_float(eC.y), v5 = __int_as_float(eC.w);
        float v6 = __int_as_float(eD.y), v7 = __int_as_float(eD.w);
        #pragma unroll
        for (int j = 0; j < 8; ++j) {
            acc[j] = fmaf(v0, b2f(x0[j]), acc[j]);
            acc[j] = fmaf(v1, b2f(x1[j]), acc[j]);
            acc[j] = fmaf(v2, b2f(x2[j]), acc[j]);
            acc[j] = fmaf(v3, b2f(x3[j]), acc[j]);
            acc[j] = fmaf(v4, b2f(x4[j]), acc[j]);
            acc[j] = fmaf(v5, b2f(x5[j]), acc[j]);
            acc[j] = fmaf(v6, b2f(x6[j]), acc[j]);
            acc[j] = fmaf(v7, b2f(x7[j]), acc[j]);
        }
    }

    float4 bi0 = ((const float4*)bias)[lane * 2];
    float4 bi1 = ((const float4*)bias)[lane * 2 + 1];
    float bb[8] = { bi0.x, bi0.y, bi0.z, bi0.w, bi1.x, bi1.y, bi1.z, bi1.w };
    float r[8];
    #pragma unroll
    for (int j = 0; j < 8; ++j) {
        float v = acc[j] + bb[j];
        r[j] = (v >= 0.f) ? v : NEG_SLOPE * v;
    }
    if (LAYER == 1) {
        uint32_t e0 = (uint32_t)row * DIM + lane * 8;
        ushort8v o;
        #pragma unroll
        for (int j = 0; j < 8; ++j) {
            uint32_t o0, o1;
            threefry_42(0u, e0 + j, o0, o1);     // partitionable: bits=o0^o1, keep iff MSB clear
            uint32_t bits = o0 ^ o1;
            float v = ((int)bits >= 0) ? r[j] * 2.0f : 0.0f;
            o[j] = f2bf(v);
        }
        ((ushort8v*)outp)[(size_t)row * 64 + lane] = o;
    } else {
        float4 o0 = make_float4(r[0], r[1], r[2], r[3]);
        float4 o1 = make_float4(r[4], r[5], r[6], r[7]);
        ((float4*)outp)[(size_t)row * 128 + lane * 2]     = o0;
        ((float4*)outp)[(size_t)row * 128 + lane * 2 + 1] = o1;
    }
}

// ---------------- launch ----------------
extern "C" void kernel_launch(void* const* d_in, const int* in_sizes, int n_in,
                              void* d_out, int out_size, void* d_ws, size_t ws_size,
                              hipStream_t stream) {
    const float* H    = (const float*)d_in[0];
    const int*   rows = (const int*)  d_in[1];
    const int*   cols = (const int*)  d_in[2];
    const float* vals = (const float*)d_in[3];
    const float* W1   = (const float*)d_in[4];
    const float* b1   = (const float*)d_in[5];
    const float* W2   = (const float*)d_in[6];
    const float* b2   = (const float*)d_in[7];
    float* out = (float*)d_out;

    char* ws = (char*)d_ws;
    size_t off = 0;
    auto alloc = [&](size_t bytes) -> void* {
        off = (off + 255) & ~(size_t)255;
        void* p = ws + off;
        off += bytes;
        return p;
    };
    int*  deg   = (int*) alloc((size_t)N_NODES * 4);
    int2* epack = (int2*)alloc((size_t)N_NODES * ELL_W * 8);   // 5.12 MB ELL
    unsigned short* WT1 = (unsigned short*)alloc((size_t)DIM * DIM * 2);
    unsigned short* WT2 = (unsigned short*)alloc((size_t)DIM * DIM * 2);
    unsigned short* Abf = (unsigned short*)alloc((size_t)M_PAD * DIM * 2);
    unsigned short* hbf = (unsigned short*)alloc((size_t)M_PAD * DIM * 2);
    unsigned short* Xbf = (unsigned short*)alloc((size_t)N_NODES * DIM * 2);

    int prep_blocks = CONV_BLKS + 2 * TR_BLKS + EZ_BLKS + ZERO_BLKS;
    prep_kernel<<<prep_blocks, 256, 0, stream>>>(H, W1, W2, Abf, WT1, WT2,
                                                 (int4*)epack, deg);
    ell_scatter<<<(N_EDGES + 255) / 256, 256, 0, stream>>>(rows, cols, vals, deg, epack);

    dim3 ggrid(M_PAD / 128, DIM / 128);
    mfma_gemm<<<ggrid, 256, 0, stream>>>(Abf, WT1, Xbf, N_NODES);
    spmm_kernel<1><<<N_NODES / 4, 256, 0, stream>>>(Xbf, deg, epack, b1, hbf);
    mfma_gemm<<<ggrid, 256, 0, stream>>>(hbf, WT2, Xbf, N_NODES);
    spmm_kernel<2><<<N_NODES / 4, 256, 0, stream>>>(Xbf, deg, epack, b2, out);
}